// Round 9
// baseline (111.563 us; speedup 1.0000x reference)
//
#include <hip/hip_runtime.h>
#include <stdint.h>

#define IN_DIM 1024
#define OUT_DIM 1024
#define NROWS 8192
#define KD 3072            // B ws layout: k = (p-1)*1024 + i (k=0 folded into bias)

#define BM 256
#define BN 128
#define NIC 32             // 32 i-chunks of 32 cols; chunk = i-chunk x {p=1,2,3}

typedef __bf16 bf16x8 __attribute__((ext_vector_type(8)));
typedef float f32x4 __attribute__((ext_vector_type(4)));
typedef unsigned short us8 __attribute__((ext_vector_type(8)));
typedef unsigned int u32;

#define AS1 __attribute__((address_space(1)))
#define AS3 __attribute__((address_space(3)))

__device__ __forceinline__ unsigned short f2bf(float f) {
    u32 u = __builtin_bit_cast(u32, f);
    u32 r = (u + 0x7fffu + ((u >> 16) & 1u)) >> 16;   // RNE, finite inputs
    return (unsigned short)r;
}

__device__ __forceinline__ bf16x8 ld8(const unsigned short* p) {
    return __builtin_bit_cast(bf16x8, *reinterpret_cast<const us8*>(p));
}

// ---- prep: coeffs fp32 -> bf16 B[OUT_DIM][KD] (k-major), c0 folded into bias2 ----
__global__ __launch_bounds__(256) void prep_coeffs(const float* __restrict__ c,
                                                   const float* __restrict__ bias,
                                                   unsigned short* __restrict__ B,
                                                   float* __restrict__ bias2) {
    const int o = blockIdx.x;
    const float4* row = reinterpret_cast<const float4*>(c + (size_t)o * (IN_DIM * 4));
    unsigned short* Bo = B + (size_t)o * KD;
    float s = 0.f;
    for (int i = threadIdx.x; i < IN_DIM; i += 256) {
        float4 v = row[i];            // {c0, c1, c2, c3} for (o, i)
        s += v.x;
        Bo[i]        = f2bf(v.y);
        Bo[1024 + i] = f2bf(v.z);
        Bo[2048 + i] = f2bf(v.w);
    }
#pragma unroll
    for (int off = 32; off; off >>= 1) s += __shfl_down(s, off);
    __shared__ float red[4];
    if ((threadIdx.x & 63) == 0) red[threadIdx.x >> 6] = s;
    __syncthreads();
    if (threadIdx.x == 0) bias2[o] = bias[o] + red[0] + red[1] + red[2] + red[3];
}

// ---- fused GEMM: C[n][o] = sum_{p,i} x[n][i]^p * Bws[o][(p-1)*1024+i] + bias2 ----
// A generated in-register from x; only B LDS-staged (48 KiB). 512 thr /
// 8 waves (4M x 2N, wave 64x64). Chunk = 32 i-cols x 3 powers (48 MFMA/wave).
// KEY (round-9): conversion PIPELINED one chunk ahead — MFMA(chunk ic)
// consumes paf(ic) converted during chunk ic-1, so the VALU convert stream
// (x(ic+1) -> paf(ic+1)) is INDEPENDENT of this chunk's MFMA stream and the
// compiler interleaves them across pipes (round 8 exposed the conv->MFMA
// dependency chain every m-step: 18% matrix duty). x loads issued mid-chunk
// (after conversion frees xq), B glds at chunk top; vmcnt(0) at top drains
// loads issued ~1 chunk (~1900cyc) earlier.
__global__ __launch_bounds__(512, 1) void taylor_gemm(
    const float* __restrict__ x,            // fp32 [NROWS][IN_DIM]
    const unsigned short* __restrict__ B,   // bf16 [OUT_DIM][KD]
    const float* __restrict__ bias2,
    float* __restrict__ C) {
    __shared__ alignas(16) unsigned short sB[2][3][BN * 32];  // 2 x 3 x 8 KiB

    const int tid = threadIdx.x;
    const int lane = tid & 63;
    const int wid = tid >> 6;       // 0..7
    const int wr = wid >> 1;        // 0..3  (M quarter: 64 rows)
    const int wc = wid & 1;         // 0..1  (N half: 64 cols)
    const int gx = blockIdx.x, gy = blockIdx.y;

    // ---- B staging: 3 glds/wave/chunk; [128][32] planes, 4-slot involution ----
    const char* Bb = (const char*)B;
    const int srow = wid * 16 + (lane >> 2);             // row within 128-panel
    const int sslot = (lane & 3) ^ ((lane >> 2) & 3);    // pre-swizzled global slot
    const size_t bSrc = ((size_t)(gy * BN + srow) * KD + sslot * 8) * 2;
    const int bDst = wid * 512;                          // 16 rows x 32 ushort

    auto stage_all = [&](int d, int ic) {
        size_t koff = (size_t)ic * 64;                   // 32 cols x 2 B
#pragma unroll
        for (int pp = 0; pp < 3; ++pp)
            __builtin_amdgcn_global_load_lds(
                (const AS1 void*)(Bb + bSrc + (size_t)pp * 2048 + koff),
                (AS3 void*)(&sB[d][pp][bDst]), 16, 0, 0);
    };

    // swizzled B-frag read base (ushort idx): row r = wc*64+n*16+(lane&15),
    // slot s = lane>>4 -> addr = r*32 + ((s^(lane&3))*8)   [r&3 == lane&3]
    const int bSw = (wc * 64 + (lane & 15)) * 32 + (((lane >> 4) ^ (lane & 3)) * 8);

    // x fragment base: (m): row gx*BM + wr*64 + m*16 + (lane&15),
    // cols ic*32 + (lane>>4)*8
    const float* xb[4];
#pragma unroll
    for (int m = 0; m < 4; ++m)
        xb[m] = x + (size_t)(gx * BM + wr * 64 + m * 16 + (lane & 15)) * IN_DIM
                  + ((lane >> 4) * 8);

    float4 xq[4][2];                 // x(ic+1): 32 fp32
    bf16x8 pafA[3][4], pafB[3][4];   // converted A-frags, ping-pong (96 VGPR)
    f32x4 acc[4][4] = {};

    auto load_x = [&](int ic) {
#pragma unroll
        for (int m = 0; m < 4; ++m) {
            const float* p = xb[m] + ic * 32;
            xq[m][0] = *reinterpret_cast<const float4*>(p);
            xq[m][1] = *reinterpret_cast<const float4*>(p + 4);
        }
    };

    auto convert_all = [&](bf16x8 (&paf)[3][4]) {
#pragma unroll
        for (int m = 0; m < 4; ++m) {
            float v[8] = {xq[m][0].x, xq[m][0].y, xq[m][0].z, xq[m][0].w,
                          xq[m][1].x, xq[m][1].y, xq[m][1].z, xq[m][1].w};
            bf16x8 a0, a1, a2;
#pragma unroll
            for (int j = 0; j < 8; ++j) {
                float w1 = v[j];
                float w2 = w1 * w1;
                float w3 = w2 * w1;
                a0[j] = (__bf16)w1;
                a1[j] = (__bf16)w2;
                a2[j] = (__bf16)w3;
            }
            paf[0][m] = a0; paf[1][m] = a1; paf[2][m] = a2;
        }
    };

    auto compute = [&](int d, bf16x8 (&paf)[3][4]) {
#pragma unroll
        for (int pp = 0; pp < 3; ++pp) {
            bf16x8 fb[4];
#pragma unroll
            for (int n = 0; n < 4; ++n)
                fb[n] = ld8(&sB[d][pp][bSw + n * 16 * 32]);
            __builtin_amdgcn_s_setprio(1);
#pragma unroll
            for (int m = 0; m < 4; ++m)
#pragma unroll
                for (int n = 0; n < 4; ++n)
                    acc[m][n] = __builtin_amdgcn_mfma_f32_16x16x32_bf16(
                        paf[pp][m], fb[n], acc[m][n], 0, 0, 0);
            __builtin_amdgcn_s_setprio(0);
        }
    };

    // prologue: x(0)+B(0); convert paf(0); issue x(1)
    load_x(0);
    stage_all(0, 0);
    asm volatile("s_waitcnt vmcnt(0)" ::: "memory");
    __builtin_amdgcn_s_barrier();
    __builtin_amdgcn_sched_barrier(0);
    convert_all(pafA);
    load_x(1);

    // chunk ic: wait(B(ic), x(ic+1) landed) -> barrier -> stage B(ic+1) ->
    // convert x(ic+1)->paf(ic+1)  [VALU, independent]  ||  MFMA paf(ic)  ->
    // issue x(ic+2) mid-chunk (xq WAR after conversion).
#define TAYLOR_CHUNK(ic, CUR, NXT)                                            \
    {                                                                         \
        asm volatile("s_waitcnt vmcnt(0)" ::: "memory");                      \
        __builtin_amdgcn_s_barrier();                                         \
        __builtin_amdgcn_sched_barrier(0);                                    \
        if ((ic) + 1 < NIC) stage_all(((ic) + 1) & 1, (ic) + 1);              \
        if ((ic) + 1 < NIC) convert_all(NXT);                                 \
        if ((ic) + 2 < NIC) load_x((ic) + 2);                                 \
        compute((ic) & 1, CUR);                                               \
    }

    for (int ic = 0; ic < NIC; ic += 2) {
        TAYLOR_CHUNK(ic,     pafA, pafB);
        TAYLOR_CHUNK(ic + 1, pafB, pafA);
    }
#undef TAYLOR_CHUNK

    // epilogue: C/D layout col = lane&15, row = (lane>>4)*4 + r
    const int colBase = gy * BN + wc * 64 + (lane & 15);
    const int rowBase = gx * BM + wr * 64 + (lane >> 4) * 4;
#pragma unroll
    for (int n = 0; n < 4; ++n) {
        int col = colBase + n * 16;
        float bv = bias2[col];
#pragma unroll
        for (int m = 0; m < 4; ++m) {
            int row = rowBase + m * 16;
#pragma unroll
            for (int r = 0; r < 4; ++r)
                C[(size_t)(row + r) * OUT_DIM + col] = acc[m][n][r] + bv;
        }
    }
}

// ---- fallback (ws too small): fp32 LDS-staged, correct but slow ----
__global__ void taylor_naive(const float* __restrict__ x, const float* __restrict__ coeffs,
                             const float* __restrict__ bias, float* __restrict__ out) {
    int n = blockIdx.x;
    __shared__ float P[IN_DIM * 4];
    for (int i = threadIdx.x; i < IN_DIM; i += blockDim.x) {
        float xv = x[(size_t)n * IN_DIM + i];
        P[i * 4 + 0] = 1.f;
        P[i * 4 + 1] = xv;
        P[i * 4 + 2] = xv * xv;
        P[i * 4 + 3] = xv * xv * xv;
    }
    __syncthreads();
    for (int o = threadIdx.x; o < OUT_DIM; o += blockDim.x) {
        float s = bias[o];
        const float* c = coeffs + (size_t)o * (IN_DIM * 4);
        for (int i = 0; i < IN_DIM; ++i) {
            float4 cv = *reinterpret_cast<const float4*>(c + i * 4);
            s += cv.x * P[i * 4 + 0] + cv.y * P[i * 4 + 1] +
                 cv.z * P[i * 4 + 2] + cv.w * P[i * 4 + 3];
        }
        out[(size_t)n * OUT_DIM + o] = s;
    }
}

extern "C" void kernel_launch(void* const* d_in, const int* in_sizes, int n_in,
                              void* d_out, int out_size, void* d_ws, size_t ws_size,
                              hipStream_t stream) {
    const float* x = (const float*)d_in[0];
    const float* coeffs = (const float*)d_in[1];
    const float* bias = (const float*)d_in[2];
    float* out = (float*)d_out;

    const size_t needB = (size_t)OUT_DIM * KD * 2;   // 6 MiB
    const size_t needBias = OUT_DIM * sizeof(float); // 4 KiB

    if (ws_size >= needB + needBias) {
        unsigned short* B = (unsigned short*)d_ws;
        float* bias2 = (float*)((char*)d_ws + needB);
        prep_coeffs<<<OUT_DIM, 256, 0, stream>>>(coeffs, bias, B, bias2);
        dim3 grid(NROWS / BM, OUT_DIM / BN);   // (32, 8) = 256 blocks, 1/CU
        taylor_gemm<<<grid, 512, 0, stream>>>(x, B, bias2, out);
    } else {
        taylor_naive<<<NROWS, 256, 0, stream>>>(x, coeffs, bias, out);
    }
}

// Round 10
// 76.858 us; speedup vs baseline: 1.4515x; 1.4515x over previous
//
#include <hip/hip_runtime.h>
#include <stdint.h>

#define IN_DIM 1024
#define OUT_DIM 1024
#define NROWS 8192
#define KD 3072            // k-major: K = (p-1)*1024 + i, p = 1..3 (k=0 folded into bias)

#define BM 128
#define BN 128
#define BK 64
#define NT (KD / BK)       // 48 K-tiles

typedef __bf16 bf16x8 __attribute__((ext_vector_type(8)));
typedef float f32x4 __attribute__((ext_vector_type(4)));
typedef unsigned short us8 __attribute__((ext_vector_type(8)));
typedef unsigned int u32;

#define AS1 __attribute__((address_space(1)))
#define AS3 __attribute__((address_space(3)))

__device__ __forceinline__ unsigned short f2bf(float f) {
    u32 u = __builtin_bit_cast(u32, f);
    u32 r = (u + 0x7fffu + ((u >> 16) & 1u)) >> 16;   // RNE, finite inputs
    return (unsigned short)r;
}

__device__ __forceinline__ bf16x8 ld8(const unsigned short* p) {
    return __builtin_bit_cast(bf16x8, *reinterpret_cast<const us8*>(p));
}

// ---- prep: coeffs fp32 -> bf16 B[OUT_DIM][KD] (k-major), c0 folded into bias2 ----
__global__ __launch_bounds__(256) void prep_coeffs(const float* __restrict__ c,
                                                   const float* __restrict__ bias,
                                                   unsigned short* __restrict__ B,
                                                   float* __restrict__ bias2) {
    const int o = blockIdx.x;
    const float4* row = reinterpret_cast<const float4*>(c + (size_t)o * (IN_DIM * 4));
    unsigned short* Bo = B + (size_t)o * KD;
    float s = 0.f;
    for (int i = threadIdx.x; i < IN_DIM; i += 256) {
        float4 v = row[i];            // {c0, c1, c2, c3} for (o, i)
        s += v.x;
        Bo[i]        = f2bf(v.y);
        Bo[1024 + i] = f2bf(v.z);
        Bo[2048 + i] = f2bf(v.w);
    }
#pragma unroll
    for (int off = 32; off; off >>= 1) s += __shfl_down(s, off);
    __shared__ float red[4];
    if ((threadIdx.x & 63) == 0) red[threadIdx.x >> 6] = s;
    __syncthreads();
    if (threadIdx.x == 0) bias2[o] = bias[o] + red[0] + red[1] + red[2] + red[3];
}

// ---- prep: powers of x -> bf16 A[NROWS][KD] (k-major) ----
__global__ __launch_bounds__(256) void prep_powers(const float* __restrict__ x,
                                                   unsigned short* __restrict__ A) {
    int t = blockIdx.x * blockDim.x + threadIdx.x;    // each handles 4 x values
    int n = t >> 8;                                   // 256 float4 per row
    int i4 = (t & 255) * 4;
    float4 v = reinterpret_cast<const float4*>(x)[t];
    unsigned short* An = A + (size_t)n * KD + i4;
    float xs[4] = {v.x, v.y, v.z, v.w};
    unsigned short b1[4], b2[4], b3[4];
#pragma unroll
    for (int j = 0; j < 4; ++j) {
        float x1 = xs[j], x2 = x1 * x1, x3 = x2 * x1;
        b1[j] = f2bf(x1); b2[j] = f2bf(x2); b3[j] = f2bf(x3);
    }
    ushort4 p1 = {b1[0], b1[1], b1[2], b1[3]};
    ushort4 p2 = {b2[0], b2[1], b2[2], b2[3]};
    ushort4 p3 = {b3[0], b3[1], b3[2], b3[3]};
    *reinterpret_cast<ushort4*>(An)        = p1;
    *reinterpret_cast<ushort4*>(An + 1024) = p2;
    *reinterpret_cast<ushort4*>(An + 2048) = p3;
}

// ---- main GEMM: C = A[M][KD] * B[N][KD]^T + bias2 ----
// 128x128 tile, 256 thr / 4 waves (2M x 2N, wave 64x64), BK=64.
// Double-buffered LDS (64 KiB) -> 2 blocks/CU: co-resident block hides the
// 2-phase stage/vmcnt/barrier overhead (the m97 occupancy mechanism).
// UNPINNED compute: 16 frag ds_reads issued up front, MFMA cluster free —
// compiler emits fine-grained counted lgkm waits (no m141-style pins, no
// setprio per m190 lockstep result). T2 XOR-swizzle pair (conflicts=0).
__global__ __launch_bounds__(256, 2) void taylor_gemm(
    const unsigned short* __restrict__ A,   // bf16 [NROWS][KD]
    const unsigned short* __restrict__ B,   // bf16 [OUT_DIM][KD]
    const float* __restrict__ bias2,
    float* __restrict__ C) {
    __shared__ alignas(16) unsigned short sA[2][BM * BK];  // 2 x 16 KiB
    __shared__ alignas(16) unsigned short sB[2][BN * BK];  // 2 x 16 KiB

    const int tid = threadIdx.x;
    const int lane = tid & 63;
    const int wid = tid >> 6;       // 0..3
    const int wr = wid >> 1;        // 0..1  (M half: 64 rows)
    const int wc = wid & 1;         // 0..1  (N half: 64 cols)
    const int gx = blockIdx.x, gy = blockIdx.y;

    // ---- staging: 8 gld_lds units/wave/tile (A:4, B:4), T2 source swizzle ----
    // LDS dest linear (base + lane*16); source col-slot XOR-permuted so the
    // swizzled read addr r*128B + (s^(r&7))*16B yields global slot s.
    const char* Ab = (const char*)A;
    const char* Bb = (const char*)B;
    const int cs = ((lane & 7) ^ (lane >> 3)) * 8;   // swizzled source col (ushort)
    size_t aSrc[4], bSrc[4];
    int dstOff[4];
#pragma unroll
    for (int u = 0; u < 4; ++u) {
        int row = u * 32 + wid * 8 + (lane >> 3);    // 0..127 within tile
        aSrc[u] = ((size_t)(gx * BM + row) * KD + cs) * 2;
        bSrc[u] = ((size_t)(gy * BN + row) * KD + cs) * 2;
        dstOff[u] = row * BK - (lane >> 3) * BK;     // wave-uniform base (row - lane part)
    }

    auto stage_all = [&](int d, int kt) {
        size_t koff = (size_t)kt * (BK * 2);
#pragma unroll
        for (int u = 0; u < 4; ++u)
            __builtin_amdgcn_global_load_lds(
                (const AS1 void*)(Ab + aSrc[u] + koff),
                (AS3 void*)(&sA[d][dstOff[u]]), 16, 0, 0);
#pragma unroll
        for (int u = 0; u < 4; ++u)
            __builtin_amdgcn_global_load_lds(
                (const AS1 void*)(Bb + bSrc[u] + koff),
                (AS3 void*)(&sB[d][dstOff[u]]), 16, 0, 0);
    };

    // swizzled fragment read bases (ushort index), per ks:
    // row r = waveHalf*64 + frag*16 + (lane&15)  (r&7 == lane&7)
    // slot s = ks*4 + (lane>>4);  addr = r*64 + (s ^ (lane&7))*8
    int aSw[2], bSw[2];
#pragma unroll
    for (int ks = 0; ks < 2; ++ks) {
        int sw = ((ks * 4 + (lane >> 4)) ^ (lane & 7)) * 8;
        aSw[ks] = (wr * 64 + (lane & 15)) * BK + sw;
        bSw[ks] = (wc * 64 + (lane & 15)) * BK + sw;
    }

    f32x4 acc[4][4] = {};

    // prologue: stage tile 0 -> buf 0
    stage_all(0, 0);
    asm volatile("s_waitcnt vmcnt(0)" ::: "memory");
    __builtin_amdgcn_s_barrier();
    __builtin_amdgcn_sched_barrier(0);

    for (int kt = 0; kt < NT; ++kt) {
        const int d = kt & 1;
        const unsigned short* sAc = &sA[d][0];
        const unsigned short* sBc = &sB[d][0];

        // issue ALL fragment reads for this tile (16 x ds_read_b128), unpinned
        bf16x8 af[4][2], bf[4][2];
#pragma unroll
        for (int m = 0; m < 4; ++m)
#pragma unroll
            for (int ks = 0; ks < 2; ++ks)
                af[m][ks] = ld8(&sAc[aSw[ks] + m * 16 * BK]);
#pragma unroll
        for (int n = 0; n < 4; ++n)
#pragma unroll
            for (int ks = 0; ks < 2; ++ks)
                bf[n][ks] = ld8(&sBc[bSw[ks] + n * 16 * BK]);

        // prefetch next tile into the other buffer (other block's waves hide
        // the residual latency at the end-of-tile vmcnt)
        if (kt + 1 < NT) stage_all(d ^ 1, kt + 1);

        // MFMA cluster — compiler interleaves with counted lgkm waits
#pragma unroll
        for (int m = 0; m < 4; ++m)
#pragma unroll
            for (int n = 0; n < 4; ++n)
#pragma unroll
                for (int ks = 0; ks < 2; ++ks)
                    acc[m][n] = __builtin_amdgcn_mfma_f32_16x16x32_bf16(
                        af[m][ks], bf[n][ks], acc[m][n], 0, 0, 0);

        // tile handoff: own glds landed, then block-wide barrier
        asm volatile("s_waitcnt vmcnt(0)" ::: "memory");
        __builtin_amdgcn_s_barrier();
        __builtin_amdgcn_sched_barrier(0);   // keep next tile's ds_reads below
    }

    // epilogue: C/D layout col = lane&15, row = (lane>>4)*4 + r
    const int colBase = gy * BN + wc * 64 + (lane & 15);
    const int rowBase = gx * BM + wr * 64 + (lane >> 4) * 4;
#pragma unroll
    for (int n = 0; n < 4; ++n) {
        int col = colBase + n * 16;
        float bv = bias2[col];
#pragma unroll
        for (int m = 0; m < 4; ++m) {
            int row = rowBase + m * 16;
#pragma unroll
            for (int r = 0; r < 4; ++r)
                C[(size_t)(row + r) * OUT_DIM + col] = acc[m][n][r] + bv;
        }
    }
}

// ---- fallback (ws too small): fp32 LDS-staged, correct but slow ----
__global__ void taylor_naive(const float* __restrict__ x, const float* __restrict__ coeffs,
                             const float* __restrict__ bias, float* __restrict__ out) {
    int n = blockIdx.x;
    __shared__ float P[IN_DIM * 4];
    for (int i = threadIdx.x; i < IN_DIM; i += blockDim.x) {
        float xv = x[(size_t)n * IN_DIM + i];
        P[i * 4 + 0] = 1.f;
        P[i * 4 + 1] = xv;
        P[i * 4 + 2] = xv * xv;
        P[i * 4 + 3] = xv * xv * xv;
    }
    __syncthreads();
    for (int o = threadIdx.x; o < OUT_DIM; o += blockDim.x) {
        float s = bias[o];
        const float* c = coeffs + (size_t)o * (IN_DIM * 4);
        for (int i = 0; i < IN_DIM; ++i) {
            float4 cv = *reinterpret_cast<const float4*>(c + i * 4);
            s += cv.x * P[i * 4 + 0] + cv.y * P[i * 4 + 1] +
                 cv.z * P[i * 4 + 2] + cv.w * P[i * 4 + 3];
        }
        out[(size_t)n * OUT_DIM + o] = s;
    }
}

extern "C" void kernel_launch(void* const* d_in, const int* in_sizes, int n_in,
                              void* d_out, int out_size, void* d_ws, size_t ws_size,
                              hipStream_t stream) {
    const float* x = (const float*)d_in[0];
    const float* coeffs = (const float*)d_in[1];
    const float* bias = (const float*)d_in[2];
    float* out = (float*)d_out;

    const size_t needA = (size_t)NROWS * KD * 2;     // 48 MiB
    const size_t needB = (size_t)OUT_DIM * KD * 2;   // 6 MiB
    const size_t needBias = OUT_DIM * sizeof(float); // 4 KiB

    if (ws_size >= needA + needB + needBias) {
        unsigned short* A = (unsigned short*)d_ws;
        unsigned short* B = (unsigned short*)((char*)d_ws + needA);
        float* bias2 = (float*)((char*)d_ws + needA + needB);
        prep_coeffs<<<OUT_DIM, 256, 0, stream>>>(coeffs, bias, B, bias2);
        prep_powers<<<(NROWS * IN_DIM / 4) / 256, 256, 0, stream>>>(x, A);
        dim3 grid(NROWS / BM, OUT_DIM / BN);   // (64, 8) = 512 blocks, 2/CU
        taylor_gemm<<<grid, 256, 0, stream>>>(A, B, bias2, out);
    } else {
        taylor_naive<<<NROWS, 256, 0, stream>>>(x, coeffs, bias, out);
    }
}